// Round 12
// baseline (363.716 us; speedup 1.0000x reference)
//
#include <hip/hip_runtime.h>

// LinearShift: out = round_to_fixed(x) @ v.T + round_to_fixed(bias)
// f16 MFMA GEMM, fp32 accum: absmax 0.0 validated (rounds 7, 10, 11).
//
// 256x256, BK=64, 512 thr (8 waves 2x4), 4 phases/K-tile.
// ROUND 12: gates (vmcnt+barrier) moved BEFORE each phase's MFMA -> each
// phase's ds_reads share a barrier-free region with the previous MFMA
// cluster (m196 interleave). 3 barriers/K-tile (was 8). 2-tile manual
// unroll so P1's 12-read block overlaps prior P4's MFMA. Ledger:
//   entering tile: {B1,A1}@cur outstanding (4).
//   P1: reads A0,B0; stage A0'(+2=6); vmcnt(4) retires B1; barrier; MFMA00
//   P2: reads B1;    stage B0'(+2=6); vmcnt(4) retires A1; barrier; MFMA01
//   P3: reads A1;    stage B1'(+2=6);              (no gate)        MFMA11
//   P4:              stage A1'(+2=8); vmcnt(4) retires A0',B0'; barrier; MFMA10
//   Last tile (no stages): P1 drains vmcnt(0); P2/P4 gates skipped.

typedef _Float16 half8 __attribute__((ext_vector_type(8)));
typedef _Float16 half4v __attribute__((ext_vector_type(4)));
typedef float floatx4 __attribute__((ext_vector_type(4)));

__device__ __forceinline__ float qfix(float x) {
    float r = floorf(x * 256.0f + 0.5f);
    r = fminf(fmaxf(r, -32768.0f), 32767.0f);
    return r * 0.00390625f;
}

__global__ __launch_bounds__(256) void quantize_x_kernel(
        const float* __restrict__ x, _Float16* __restrict__ xq, int n4) {
    int i = blockIdx.x * 256 + threadIdx.x;
    const int stride = gridDim.x * 256;
    for (; i < n4; i += stride) {
        float4 v = reinterpret_cast<const float4*>(x)[i];
        half4v o;
        o[0] = (_Float16)qfix(v.x);
        o[1] = (_Float16)qfix(v.y);
        o[2] = (_Float16)qfix(v.z);
        o[3] = (_Float16)qfix(v.w);
        reinterpret_cast<half4v*>(xq)[i] = o;
    }
}

__global__ __launch_bounds__(256) void make_v_kernel(
        const float* __restrict__ shift, const float* __restrict__ sign,
        _Float16* __restrict__ v, int n4) {
    int i = blockIdx.x * 256 + threadIdx.x;
    const int stride = gridDim.x * 256;
    for (; i < n4; i += stride) {
        float4 sh = reinterpret_cast<const float4*>(shift)[i];
        float4 sg = reinterpret_cast<const float4*>(sign)[i];
        half4v o;
        o[0] = (_Float16)ldexpf((rintf(sg.x) == 0.0f) ? 1.0f : -1.0f, (int)rintf(sh.x));
        o[1] = (_Float16)ldexpf((rintf(sg.y) == 0.0f) ? 1.0f : -1.0f, (int)rintf(sh.y));
        o[2] = (_Float16)ldexpf((rintf(sg.z) == 0.0f) ? 1.0f : -1.0f, (int)rintf(sh.z));
        o[3] = (_Float16)ldexpf((rintf(sg.w) == 0.0f) ? 1.0f : -1.0f, (int)rintf(sh.w));
        reinterpret_cast<half4v*>(v)[i] = o;
    }
}

__device__ __forceinline__ void async_load16(const void* g, void* l) {
    __builtin_amdgcn_global_load_lds(
        (const __attribute__((address_space(1))) unsigned int*)g,
        (__attribute__((address_space(3))) unsigned int*)l,
        16, 0, 0);
}

// Stage one half-tile (128 rows x 64 f16 = 16KB) with XOR-swizzled source:
// LDS (linear in t) position (r, blk) holds G[row0+r][k0 + (blk^(r&7))*8].
__device__ __forceinline__ void stage_half(const _Float16* __restrict__ G, int ldg,
                                           int row0, int k0, _Float16* lds_half, int t) {
    #pragma unroll
    for (int l = 0; l < 2; ++l) {
        const int r  = l * 64 + (t >> 3);
        const int cb = (t & 7) ^ (r & 7);
        async_load16(G + (size_t)(row0 + r) * ldg + (k0 + cb * 8),
                     lds_half + l * 4096 + t * 8);
    }
}

// Swizzled fragment read: undoes the write-side XOR (0 conflicts measured).
__device__ __forceinline__ half8 read_frag(const _Float16* hb, int r, int ks, int fko) {
    const int blk = (ks * 4 + fko) ^ (r & 7);
    return *reinterpret_cast<const half8*>(hb + r * 64 + blk * 8);
}

#define MFMA_QUAD(ACCQ, BF)                                               \
    _Pragma("unroll")                                                     \
    for (int mf = 0; mf < 4; ++mf)                                        \
      _Pragma("unroll")                                                   \
      for (int nf = 0; nf < 2; ++nf)                                      \
        _Pragma("unroll")                                                 \
        for (int ks = 0; ks < 2; ++ks)                                    \
          ACCQ[mf][nf] = __builtin_amdgcn_mfma_f32_16x16x32_f16(          \
              af[mf][ks], BF[nf][ks], ACCQ[mf][nf], 0, 0, 0);

#define READ_AF(HALF)                                                     \
    _Pragma("unroll")                                                     \
    for (int mf = 0; mf < 4; ++mf)                                        \
      _Pragma("unroll")                                                   \
      for (int ks = 0; ks < 2; ++ks)                                      \
        af[mf][ks] = read_frag((HALF), wrow * 64 + mf * 16 + fr, ks, fko);

#define READ_BF(DST, HALF)                                                \
    _Pragma("unroll")                                                     \
    for (int nf = 0; nf < 2; ++nf)                                        \
      _Pragma("unroll")                                                   \
      for (int ks = 0; ks < 2; ++ks)                                      \
        DST[nf][ks] = read_frag((HALF), wcol * 32 + nf * 16 + fr, ks, fko);

#define VM4()  asm volatile("s_waitcnt vmcnt(4)" ::: "memory")
#define VM0()  asm volatile("s_waitcnt vmcnt(0)" ::: "memory")
#define BAR()  __builtin_amdgcn_s_barrier()
#define PRIO_MFMA(ACCQ, BF)                                               \
    __builtin_amdgcn_s_setprio(1);                                        \
    MFMA_QUAD(ACCQ, BF);                                                  \
    __builtin_amdgcn_s_setprio(0);

// LDS (dynamic, 128KB): [slot(2)][A0,A1,B0,B1][128][64] f16, 8192 f16/half.
__global__ __launch_bounds__(512, 2) void gemm8_kernel(
        const _Float16* __restrict__ A,   // M x K
        const _Float16* __restrict__ B,   // N x K
        const float* __restrict__ bias,   // N
        float* __restrict__ C,            // M x N
        int M, int N, int K) {
    extern __shared__ _Float16 smem[];
    const int t = threadIdx.x;
    const int lane = t & 63;
    const int w = t >> 6;
    const int wrow = w >> 2;   // 0..1
    const int wcol = w & 3;    // 0..3
    const int fr  = lane & 15;
    const int fko = lane >> 4; // 0..3

    // T1: bijective XCD swizzle (nwg % 8 == 0 for this shape)
    const int nwg = gridDim.x;
    const int bid = blockIdx.x;
    const int cpx = nwg >> 3;
    const int swz = (bid & 7) * cpx + (bid >> 3);
    const int ntN = N >> 8;
    const int bm = (swz / ntN) << 8;
    const int bn = (swz % ntN) << 8;

    // prologue: stage K-tile 0 into slot 0, drain once
    stage_half(A, K, bm,       0, smem,         t);
    stage_half(B, K, bn,       0, smem + 16384, t);
    stage_half(B, K, bn + 128, 0, smem + 24576, t);
    stage_half(A, K, bm + 128, 0, smem + 8192,  t);
    VM0();
    BAR();

    floatx4 acc[2][2][4][2] = {};   // [qm][qn][mf][nf] — all static-indexed
    const int NT = K >> 6;          // even (K=4096 -> 64)

    auto tile_body = [&](const _Float16* cb, _Float16* nb, int k1, bool more)
            __attribute__((always_inline)) {
        const _Float16* cA0 = cb;
        const _Float16* cA1 = cb + 8192;
        const _Float16* cB0 = cb + 16384;
        const _Float16* cB1 = cb + 24576;
        half8 af[4][2], bf0[2][2], bf1[2][2];

        // P1: reads (overlap prior MFMA region); stage A0'; gate B1; MFMA00
        READ_AF(cA0);
        READ_BF(bf0, cB0);
        if (more) { stage_half(A, K, bm, k1, nb, t); VM4(); }
        else      { VM0(); }
        BAR();
        PRIO_MFMA(acc[0][0], bf0);

        // P2: reads B1 (overlap MFMA00); stage B0'; gate A1; MFMA01
        READ_BF(bf1, cB1);
        if (more) { stage_half(B, K, bn, k1, nb + 16384, t); VM4(); BAR(); }
        PRIO_MFMA(acc[0][1], bf1);

        // P3: reads A1 (overlap MFMA01); stage B1'; no gate; MFMA11
        READ_AF(cA1);
        if (more) stage_half(B, K, bn + 128, k1, nb + 24576, t);
        PRIO_MFMA(acc[1][1], bf1);

        // P4: no reads; stage A1'; gate {A0',B0'}; MFMA10 (next reads overlap)
        if (more) { stage_half(A, K, bm + 128, k1, nb + 8192, t); VM4(); BAR(); }
        PRIO_MFMA(acc[1][0], bf0);
    };

    _Float16* slot0 = smem;
    _Float16* slot1 = smem + 32768;
    for (int kt = 0; kt < NT; kt += 2) {
        tile_body(slot0, slot1, (kt + 1) << 6, true);
        tile_body(slot1, slot0, (kt + 2) << 6, (kt + 2) < NT);
    }

    // Epilogue: C/D layout col=lane&15, row=(lane>>4)*4+reg (validated)
    #pragma unroll
    for (int qm = 0; qm < 2; ++qm)
      #pragma unroll
      for (int qn = 0; qn < 2; ++qn)
        #pragma unroll
        for (int nf = 0; nf < 2; ++nf) {
            const int gcol = bn + qn * 128 + wcol * 32 + nf * 16 + (lane & 15);
            const float bq = qfix(bias[gcol]);
            #pragma unroll
            for (int mf = 0; mf < 4; ++mf) {
                const int grow = bm + qm * 128 + wrow * 64 + mf * 16 + ((lane >> 4) << 2);
                float* p = C + (size_t)grow * N + gcol;
                #pragma unroll
                for (int r = 0; r < 4; ++r)
                    p[(size_t)r * N] = acc[qm][qn][mf][nf][r] + bq;
            }
        }
}

extern "C" void kernel_launch(void* const* d_in, const int* in_sizes, int n_in,
                              void* d_out, int out_size, void* d_ws, size_t ws_size,
                              hipStream_t stream) {
    const float* x     = (const float*)d_in[0];
    const float* shift = (const float*)d_in[1];
    const float* sign  = (const float*)d_in[2];
    const float* bias  = (const float*)d_in[3];
    float* out = (float*)d_out;

    const int N = in_sizes[3];            // 4096
    const int K = in_sizes[1] / N;        // 4096
    const int M = in_sizes[0] / K;        // 8192

    _Float16* xq = (_Float16*)d_ws;
    _Float16* v  = (_Float16*)((char*)d_ws + (size_t)M * K * sizeof(_Float16));

    quantize_x_kernel<<<2048, 256, 0, stream>>>(x, xq, M * K / 4);
    make_v_kernel<<<2048, 256, 0, stream>>>(shift, sign, v, N * K / 4);

    (void)hipFuncSetAttribute(reinterpret_cast<const void*>(gemm8_kernel),
                              hipFuncAttributeMaxDynamicSharedMemorySize, 131072);
    const int nblk = (M / 256) * (N / 256);
    gemm8_kernel<<<nblk, 512, 131072, stream>>>(xq, v, bias, out, M, N, K);
}

// Round 13
// 306.692 us; speedup vs baseline: 1.1859x; 1.1859x over previous
//
#include <hip/hip_runtime.h>

// LinearShift: out = round_to_fixed(x) @ v.T + round_to_fixed(bias)
// f16 MFMA GEMM, fp32 accum: absmax 0.0 validated (rounds 7, 10, 11).
//
// 256x256, BK=64, 512 thr (8 waves 2x4), 4 phases/K-tile, r10's validated
// ledger (3x vmcnt(4), last-tile vmcnt(0) drain), dual barriers per phase.
// ROUND 13 (r12 reverted — gate-before-MFMA + barrier removal regressed 18%):
// strength-reduced addressing only:
//  - 4 running global stage pointers (+64 els/tile), l=1 row via SGPR 64*K
//  - precomputed swizzled LDS read vaddrs (XOR term is row-invariant) ->
//    every ds_read_b128 is vaddr+imm, 0 VALU in steady state
//  - bf single-buffered (P4 re-reads B0) to keep VGPR+AGPR < 256

typedef _Float16 half8 __attribute__((ext_vector_type(8)));
typedef _Float16 half4v __attribute__((ext_vector_type(4)));
typedef float floatx4 __attribute__((ext_vector_type(4)));

__device__ __forceinline__ float qfix(float x) {
    float r = floorf(x * 256.0f + 0.5f);
    r = fminf(fmaxf(r, -32768.0f), 32767.0f);
    return r * 0.00390625f;
}

__global__ __launch_bounds__(256) void quantize_x_kernel(
        const float* __restrict__ x, _Float16* __restrict__ xq, int n4) {
    int i = blockIdx.x * 256 + threadIdx.x;
    const int stride = gridDim.x * 256;
    for (; i < n4; i += stride) {
        float4 v = reinterpret_cast<const float4*>(x)[i];
        half4v o;
        o[0] = (_Float16)qfix(v.x);
        o[1] = (_Float16)qfix(v.y);
        o[2] = (_Float16)qfix(v.z);
        o[3] = (_Float16)qfix(v.w);
        reinterpret_cast<half4v*>(xq)[i] = o;
    }
}

__global__ __launch_bounds__(256) void make_v_kernel(
        const float* __restrict__ shift, const float* __restrict__ sign,
        _Float16* __restrict__ v, int n4) {
    int i = blockIdx.x * 256 + threadIdx.x;
    const int stride = gridDim.x * 256;
    for (; i < n4; i += stride) {
        float4 sh = reinterpret_cast<const float4*>(shift)[i];
        float4 sg = reinterpret_cast<const float4*>(sign)[i];
        half4v o;
        o[0] = (_Float16)ldexpf((rintf(sg.x) == 0.0f) ? 1.0f : -1.0f, (int)rintf(sh.x));
        o[1] = (_Float16)ldexpf((rintf(sg.y) == 0.0f) ? 1.0f : -1.0f, (int)rintf(sh.y));
        o[2] = (_Float16)ldexpf((rintf(sg.z) == 0.0f) ? 1.0f : -1.0f, (int)rintf(sh.z));
        o[3] = (_Float16)ldexpf((rintf(sg.w) == 0.0f) ? 1.0f : -1.0f, (int)rintf(sh.w));
        reinterpret_cast<half4v*>(v)[i] = o;
    }
}

__device__ __forceinline__ void async_load16(const void* g, void* l) {
    __builtin_amdgcn_global_load_lds(
        (const __attribute__((address_space(1))) unsigned int*)g,
        (__attribute__((address_space(3))) unsigned int*)l,
        16, 0, 0);
}

// Stage one half-tile from running pointer P (rows r0 and r0+64, col block
// cb pre-folded into P). LDS dest linear: dst + t*8 / +4096 + t*8.
// LDS content: LDS[r][b] = G[row0+r][k0 + (b^(r&7))*8]  (b = t&7, r&7 = r0&7).
#define STAGE(P, DST) do {                                                \
    async_load16((P), (DST) + t * 8);                                     \
    async_load16((P) + skip, (DST) + 4096 + t * 8); } while (0)

#define MFMA_QUAD(ACCQ)                                                   \
    _Pragma("unroll")                                                     \
    for (int mf = 0; mf < 4; ++mf)                                        \
      _Pragma("unroll")                                                   \
      for (int nf = 0; nf < 2; ++nf)                                      \
        _Pragma("unroll")                                                 \
        for (int ks = 0; ks < 2; ++ks)                                    \
          ACCQ[mf][nf] = __builtin_amdgcn_mfma_f32_16x16x32_f16(          \
              af[mf][ks], bf[nf][ks], ACCQ[mf][nf], 0, 0, 0);

#define PHASE_CORE(ACCQ)                                                  \
    asm volatile("" ::: "memory");                                        \
    __builtin_amdgcn_s_barrier();                                         \
    __builtin_amdgcn_s_setprio(1);                                        \
    MFMA_QUAD(ACCQ);                                                      \
    __builtin_amdgcn_s_setprio(0);

#define END_BARRIER()                                                     \
    asm volatile("" ::: "memory");                                        \
    __builtin_amdgcn_s_barrier();

// Precomputed-vaddr reads: HOFF is the half-tile byte base within a slot
// (A0=0, A1=16384, B0=32768, B1=49152); mf/nf*2048 folds into ds_read imm.
#define READ_AF(HOFF)                                                     \
    _Pragma("unroll")                                                     \
    for (int mf = 0; mf < 4; ++mf)                                        \
      _Pragma("unroll")                                                   \
      for (int ks = 0; ks < 2; ++ks)                                      \
        af[mf][ks] = *reinterpret_cast<const half8*>(                     \
            (ks ? aR1s : aR0s) + (HOFF) + mf * 2048);

#define READ_BF(HOFF)                                                     \
    _Pragma("unroll")                                                     \
    for (int nf = 0; nf < 2; ++nf)                                        \
      _Pragma("unroll")                                                   \
      for (int ks = 0; ks < 2; ++ks)                                      \
        bf[nf][ks] = *reinterpret_cast<const half8*>(                     \
            (ks ? bR1s : bR0s) + (HOFF) + nf * 2048);

#define VM4()  asm volatile("s_waitcnt vmcnt(4)" ::: "memory")
#define VM0()  asm volatile("s_waitcnt vmcnt(0)" ::: "memory")

// LDS (dynamic, 128KB): [slot(2)][A0,A1,B0,B1][128][64] f16, 8192 f16/half.
__global__ __launch_bounds__(512, 2) void gemm8_kernel(
        const _Float16* __restrict__ A,   // M x K
        const _Float16* __restrict__ B,   // N x K
        const float* __restrict__ bias,   // N
        float* __restrict__ C,            // M x N
        int M, int N, int K) {
    extern __shared__ _Float16 smem[];
    const int t = threadIdx.x;
    const int lane = t & 63;
    const int w = t >> 6;
    const int wrow = w >> 2;   // 0..1
    const int wcol = w & 3;    // 0..3
    const int fr  = lane & 15;
    const int fko = lane >> 4; // 0..3

    // T1: bijective XCD swizzle (nwg % 8 == 0 for this shape)
    const int nwg = gridDim.x;
    const int bid = blockIdx.x;
    const int cpx = nwg >> 3;
    const int swz = (bid & 7) * cpx + (bid >> 3);
    const int ntN = N >> 8;
    const int bm = (swz / ntN) << 8;
    const int bn = (swz % ntN) << 8;

    // Running global stage pointers (advance +64 els/tile). cb is l-invariant.
    const int r0  = t >> 3;
    const int cbo = ((t & 7) ^ (r0 & 7)) * 8;
    const _Float16* pA0 = A + (size_t)(bm +       r0) * K + cbo;
    const _Float16* pA1 = A + (size_t)(bm + 128 + r0) * K + cbo;
    const _Float16* pB0 = B + (size_t)(bn +       r0) * K + cbo;
    const _Float16* pB1 = B + (size_t)(bn + 128 + r0) * K + cbo;
    const size_t skip = (size_t)64 * K;   // l=1 row offset (SGPR)

    // Precomputed swizzled LDS read vaddrs (slot-0 based, bytes).
    const int fr7 = fr & 7;
    const int xk0 = ((0 * 4 + fko) ^ fr7) * 16;
    const int xk1 = ((1 * 4 + fko) ^ fr7) * 16;
    const char* sbase = (const char*)smem;
    const char* aR0 = sbase + (wrow * 64 + fr) * 128 + xk0;
    const char* aR1 = sbase + (wrow * 64 + fr) * 128 + xk1;
    const char* bR0 = sbase + (wcol * 32 + fr) * 128 + xk0;
    const char* bR1 = sbase + (wcol * 32 + fr) * 128 + xk1;

    // prologue: stage K-tile 0 into slot 0, drain once; advance pointers
    STAGE(pA0, smem);            // A0
    STAGE(pB0, smem + 16384);    // B0
    STAGE(pB1, smem + 24576);    // B1
    STAGE(pA1, smem + 8192);     // A1
    VM0();
    __builtin_amdgcn_s_barrier();
    pA0 += 64; pA1 += 64; pB0 += 64; pB1 += 64;

    floatx4 acc[2][2][4][2] = {};   // [qm][qn][mf][nf] — all static-indexed
    const int NT = K >> 6;

    // r10 validated ledger: entering tile kt, {B1,A1}@cur outstanding (4).
    // P1 stages A0'(+2=6) -> VM4 retires B1@cur; P2 stages B0'(+2=6) -> VM4
    // retires A1@cur; P3 stages B1'(+2=6); P4 stages A1'(+2=8) -> VM4 retires
    // {A0',B0'}. Last tile stages nothing: P1 drains VM0; P2/P4 skip gates.
    for (int kt = 0; kt < NT; ++kt) {
        const int sb = (kt & 1) << 16;          // slot byte offset for reads
        _Float16* nslot = smem + (((kt & 1) ^ 1) << 15);  // staging slot (els)
        const bool more = (kt + 1 < NT);

        const char* aR0s = aR0 + sb;
        const char* aR1s = aR1 + sb;
        const char* bR0s = bR0 + sb;
        const char* bR1s = bR1 + sb;

        half8 af[4][2], bf[2][2];

        // Phase 1: (0,0) = A0 x B0
        READ_AF(0);
        READ_BF(32768);
        if (more) STAGE(pA0, nslot);
        PHASE_CORE(acc[0][0]);
        if (more) { VM4(); } else { VM0(); }
        END_BARRIER();

        // Phase 2: (0,1) = A0 x B1
        READ_BF(49152);
        if (more) STAGE(pB0, nslot + 16384);
        PHASE_CORE(acc[0][1]);
        if (more) { VM4(); }
        END_BARRIER();

        // Phase 3: (1,1) = A1 x B1
        READ_AF(16384);
        if (more) STAGE(pB1, nslot + 24576);
        PHASE_CORE(acc[1][1]);
        END_BARRIER();

        // Phase 4: (1,0) = A1 x B0 (re-read B0; af holds A1)
        READ_BF(32768);
        if (more) STAGE(pA1, nslot + 8192);
        PHASE_CORE(acc[1][0]);
        if (more) { VM4(); }
        END_BARRIER();

        if (more) { pA0 += 64; pA1 += 64; pB0 += 64; pB1 += 64; }
    }

    // Epilogue: C/D layout col=lane&15, row=(lane>>4)*4+reg (validated)
    #pragma unroll
    for (int qm = 0; qm < 2; ++qm)
      #pragma unroll
      for (int qn = 0; qn < 2; ++qn)
        #pragma unroll
        for (int nf = 0; nf < 2; ++nf) {
            const int gcol = bn + qn * 128 + wcol * 32 + nf * 16 + (lane & 15);
            const float bq = qfix(bias[gcol]);
            #pragma unroll
            for (int mf = 0; mf < 4; ++mf) {
                const int grow = bm + qm * 128 + wrow * 64 + mf * 16 + ((lane >> 4) << 2);
                float* p = C + (size_t)grow * N + gcol;
                #pragma unroll
                for (int r = 0; r < 4; ++r)
                    p[(size_t)r * N] = acc[qm][qn][mf][nf][r] + bq;
            }
        }
}

extern "C" void kernel_launch(void* const* d_in, const int* in_sizes, int n_in,
                              void* d_out, int out_size, void* d_ws, size_t ws_size,
                              hipStream_t stream) {
    const float* x     = (const float*)d_in[0];
    const float* shift = (const float*)d_in[1];
    const float* sign  = (const float*)d_in[2];
    const float* bias  = (const float*)d_in[3];
    float* out = (float*)d_out;

    const int N = in_sizes[3];            // 4096
    const int K = in_sizes[1] / N;        // 4096
    const int M = in_sizes[0] / K;        // 8192

    _Float16* xq = (_Float16*)d_ws;
    _Float16* v  = (_Float16*)((char*)d_ws + (size_t)M * K * sizeof(_Float16));

    quantize_x_kernel<<<2048, 256, 0, stream>>>(x, xq, M * K / 4);
    make_v_kernel<<<2048, 256, 0, stream>>>(shift, sign, v, N * K / 4);

    (void)hipFuncSetAttribute(reinterpret_cast<const void*>(gemm8_kernel),
                              hipFuncAttributeMaxDynamicSharedMemorySize, 131072);
    const int nblk = (M / 256) * (N / 256);
    gemm8_kernel<<<nblk, 512, 131072, stream>>>(xq, v, bias, out, M, N, K);
}